// Round 5
// baseline (510.053 us; speedup 1.0000x reference)
//
#include <hip/hip_runtime.h>

// Strategy: the harness grades against an fp32 numpy reference. At the worst
// output elements z + 1e-6 ~ 1e-6 (catastrophic amplification ~1e11), so the
// only way under threshold is to REPRODUCE np's fp32 rounding, not to be more
// accurate (round 3 proved this: exact fp64 z made absmax 4.4x worse).
// Mimicry:
//  - Q,K,V: fp32 GEMM, sequential k ascending, explicit fmaf (= BLAS sgemm
//    microkernel accumulation order).
//  - per edge: score = f32(K*Q)*0.25f ; z += score ; wv += f32(V*score)
//    (contract(off): np never fuses mul+add).
//  - summation order: np.add.at == ascending edge order per dst. CSR by dst
//    with per-dst ascending edge ids (atomic ticket + per-dst insertion sort),
//    then sequential fp32 accumulation per (dst, channel).
//  - out = wv / (z + 1e-6f) in fp32.

// ---------------------------------------------------------------------------
// fp32 GEMM: O = h @ W, W/output selected by blockIdx.y (0:Q, 1:K, 2:V).
// Block 256, 128 rows x 128 cols; thread owns a 4x4 patch; k strictly
// ascending with single accumulator per output element (BLAS-like).
// ---------------------------------------------------------------------------
#define FMA4(acc, s, b) do { \
    (acc).x = fmaf((s), (b).x, (acc).x); \
    (acc).y = fmaf((s), (b).y, (acc).y); \
    (acc).z = fmaf((s), (b).z, (acc).z); \
    (acc).w = fmaf((s), (b).w, (acc).w); } while (0)

__global__ __launch_bounds__(256) void gemm_qkv(
    const float* __restrict__ h,
    const float* __restrict__ WQ,
    const float* __restrict__ WK,
    const float* __restrict__ WV,
    float* __restrict__ Qf,
    float* __restrict__ Kf,
    float* __restrict__ Vf,
    int N)
{
    __shared__ float4 Wl[128 * 32];  // [k][c4]  64 KB
    __shared__ float4 Hl[32 * 32];   // [row][k4] 16 KB
    const int t = threadIdx.x;
    const int which = blockIdx.y;
    const float* Wsel = (which == 0) ? WQ : ((which == 1) ? WK : WV);
    float* Osel = (which == 0) ? Qf : ((which == 1) ? Kf : Vf);
    const float4* W4 = (const float4*)Wsel;
#pragma unroll
    for (int i = 0; i < 16; ++i) Wl[t + i * 256] = W4[t + i * 256];

    const int c4 = t & 31;
    const int r4 = t >> 5;

    for (int sub = 0; sub < 4; ++sub) {
        const int r0 = (blockIdx.x * 4 + sub) * 32;
        if (r0 >= N) break;          // N % 32 == 0 (40000)
        __syncthreads();             // Hl reuse fence; covers W staging on sub==0
        const float4* H4 = (const float4*)(h + (size_t)r0 * 128);
#pragma unroll
        for (int i = 0; i < 4; ++i) Hl[t + i * 256] = H4[t + i * 256];
        __syncthreads();

        float4 acc0 = make_float4(0.f, 0.f, 0.f, 0.f);
        float4 acc1 = acc0, acc2 = acc0, acc3 = acc0;
#pragma unroll 8
        for (int k4 = 0; k4 < 32; ++k4) {
            float4 b0 = Wl[(k4 * 4 + 0) * 32 + c4];
            float4 b1 = Wl[(k4 * 4 + 1) * 32 + c4];
            float4 b2 = Wl[(k4 * 4 + 2) * 32 + c4];
            float4 b3 = Wl[(k4 * 4 + 3) * 32 + c4];
            float4 a0 = Hl[(r4 * 4 + 0) * 32 + k4];
            float4 a1 = Hl[(r4 * 4 + 1) * 32 + k4];
            float4 a2 = Hl[(r4 * 4 + 2) * 32 + k4];
            float4 a3 = Hl[(r4 * 4 + 3) * 32 + k4];
            FMA4(acc0, a0.x, b0); FMA4(acc0, a0.y, b1); FMA4(acc0, a0.z, b2); FMA4(acc0, a0.w, b3);
            FMA4(acc1, a1.x, b0); FMA4(acc1, a1.y, b1); FMA4(acc1, a1.z, b2); FMA4(acc1, a1.w, b3);
            FMA4(acc2, a2.x, b0); FMA4(acc2, a2.y, b1); FMA4(acc2, a2.z, b2); FMA4(acc2, a2.w, b3);
            FMA4(acc3, a3.x, b0); FMA4(acc3, a3.y, b1); FMA4(acc3, a3.z, b2); FMA4(acc3, a3.w, b3);
        }
        const int row = r0 + r4 * 4;
        float4* O = (float4*)Osel;
        O[(size_t)(row + 0) * 32 + c4] = acc0;
        O[(size_t)(row + 1) * 32 + c4] = acc1;
        O[(size_t)(row + 2) * 32 + c4] = acc2;
        O[(size_t)(row + 3) * 32 + c4] = acc3;
    }
}

// -------------------------- CSR build (stable by dst) ----------------------
__global__ __launch_bounds__(256) void count_deg(
    const int* __restrict__ dst, int* __restrict__ deg, int E)
{
    const int e = blockIdx.x * 256 + threadIdx.x;
    if (e < E) atomicAdd(&deg[dst[e]], 1);
}

// Single-block exclusive scan -> rowptr[0..N], 256 threads, chunked.
__global__ __launch_bounds__(256) void scan_rowptr(
    const int* __restrict__ deg, int* __restrict__ rowptr, int N)
{
    __shared__ int s[256];
    __shared__ int carry;
    const int t = threadIdx.x;
    if (t == 0) { carry = 0; rowptr[0] = 0; }
    __syncthreads();
    for (int base = 0; base < N; base += 256) {
        const int i = base + t;
        int x = (i < N) ? deg[i] : 0;
        s[t] = x;
        __syncthreads();
        for (int off = 1; off < 256; off <<= 1) {   // inclusive scan
            int v = (t >= off) ? s[t - off] : 0;
            __syncthreads();
            s[t] += v;
            __syncthreads();
        }
        if (i < N) rowptr[i + 1] = carry + s[t];
        __syncthreads();
        if (t == 255) carry += s[255];
        __syncthreads();
    }
}

__global__ __launch_bounds__(256) void scatter_eids(
    const int* __restrict__ dst, const int* __restrict__ rowptr,
    int* __restrict__ cur, int* __restrict__ eids, int E)
{
    const int e = blockIdx.x * 256 + threadIdx.x;
    if (e >= E) return;
    const int d = dst[e];
    const int pos = rowptr[d] + atomicAdd(&cur[d], 1);
    eids[pos] = e;
}

// Per-dst ascending edge ids (deg ~ Poisson(16): insertion sort is cheap).
__global__ __launch_bounds__(256) void sort_lists(
    const int* __restrict__ rowptr, int* __restrict__ eids, int N)
{
    const int n = blockIdx.x * 256 + threadIdx.x;
    if (n >= N) return;
    const int lo = rowptr[n], hi = rowptr[n + 1];
    for (int i = lo + 1; i < hi; ++i) {
        const int key = eids[i];
        int j = i - 1;
        while (j >= lo && eids[j] > key) { eids[j + 1] = eids[j]; --j; }
        eids[j + 1] = key;
    }
}

// ------------------- np.add.at-order fp32 edge accumulation ----------------
// One block per dst node, one thread per channel; strictly sequential fp32
// adds in ascending-edge order. contract(off): keep np's separate roundings.
__global__ __launch_bounds__(128) void attn_out(
    const int* __restrict__ src, const int* __restrict__ rowptr,
    const int* __restrict__ eids,
    const float* __restrict__ Kf, const float* __restrict__ Qf,
    const float* __restrict__ Vf,
    float* __restrict__ out, int N)
{
#pragma clang fp contract(off)
    const int d = blockIdx.x;
    const int c = threadIdx.x;
    const float q = Qf[(size_t)d * 128 + c];
    const int lo = rowptr[d], hi = rowptr[d + 1];
    float z = 0.f, wv = 0.f;
    for (int i = lo; i < hi; ++i) {
        const int e = eids[i];
        const int s = src[e];
        const float k = Kf[(size_t)s * 128 + c];
        const float v = Vf[(size_t)s * 128 + c];
        const float sc = (k * q) * 0.25f;  // f32(K*Q) * inv_sqrt_d (exact x0.25)
        z = z + sc;                        // np.add.at rounding, edge order
        const float p = v * sc;            // f32(V*score)
        wv = wv + p;
    }
    out[(size_t)d * 128 + c] = wv / (z + 1e-6f);
}

extern "C" void kernel_launch(void* const* d_in, const int* in_sizes, int n_in,
                              void* d_out, int out_size, void* d_ws, size_t ws_size,
                              hipStream_t stream)
{
    const float* h  = (const float*)d_in[0];
    const int* src  = (const int*)d_in[1];
    const int* dst  = (const int*)d_in[2];
    const float* WQ = (const float*)d_in[3];
    const float* WK = (const float*)d_in[4];
    const float* WV = (const float*)d_in[5];
    const int N = in_sizes[0] / 128;   // 40000
    const int E = in_sizes[1];         // 640000
    const size_t NC = (size_t)N * 128;

    // Workspace (~65 MB): Kf,Qf,Vf f32; deg,cur,rowptr,eids int.
    float* Kf = (float*)d_ws;
    float* Qf = Kf + NC;
    float* Vf = Qf + NC;
    int* deg    = (int*)(Vf + NC);
    int* cur    = deg + N;
    int* rowptr = cur + N;         // N+1 entries
    int* eids   = rowptr + (N + 1);
    float* outp = (float*)d_out;

    hipMemsetAsync(deg, 0, (size_t)2 * N * sizeof(int), stream);  // deg + cur

    dim3 ggrid((N + 127) / 128, 3);
    gemm_qkv<<<ggrid, 256, 0, stream>>>(h, WQ, WK, WV, Qf, Kf, Vf, N);

    const int eb = (E + 255) / 256;
    count_deg<<<eb, 256, 0, stream>>>(dst, deg, E);
    scan_rowptr<<<1, 256, 0, stream>>>(deg, rowptr, N);
    scatter_eids<<<eb, 256, 0, stream>>>(dst, rowptr, cur, eids, E);
    sort_lists<<<(N + 255) / 256, 256, 0, stream>>>(rowptr, eids, N);

    attn_out<<<N, 128, 0, stream>>>(src, rowptr, eids, Kf, Qf, Vf, outp, N);
}

// Round 6
// 350.035 us; speedup vs baseline: 1.4572x; 1.4572x over previous
//
#include <hip/hip_runtime.h>

// PASSED round 5 with absmax = 0.0 (bitwise match vs np reference).
// FROZEN: all fp arithmetic (gemm_qkv accumulation order, attn_out per-edge
// ops and summation order). Only integer/CSR/scheduling changes allowed.
// This round: replace the 170us single-block scan with a 3-kernel
// hierarchical scan (bit-identical rowptr, ~20x faster).

#define FMA4(acc, s, b) do { \
    (acc).x = fmaf((s), (b).x, (acc).x); \
    (acc).y = fmaf((s), (b).y, (acc).y); \
    (acc).z = fmaf((s), (b).z, (acc).z); \
    (acc).w = fmaf((s), (b).w, (acc).w); } while (0)

__global__ __launch_bounds__(256) void gemm_qkv(
    const float* __restrict__ h,
    const float* __restrict__ WQ,
    const float* __restrict__ WK,
    const float* __restrict__ WV,
    float* __restrict__ Qf,
    float* __restrict__ Kf,
    float* __restrict__ Vf,
    int N)
{
    __shared__ float4 Wl[128 * 32];  // [k][c4]  64 KB
    __shared__ float4 Hl[32 * 32];   // [row][k4] 16 KB
    const int t = threadIdx.x;
    const int which = blockIdx.y;
    const float* Wsel = (which == 0) ? WQ : ((which == 1) ? WK : WV);
    float* Osel = (which == 0) ? Qf : ((which == 1) ? Kf : Vf);
    const float4* W4 = (const float4*)Wsel;
#pragma unroll
    for (int i = 0; i < 16; ++i) Wl[t + i * 256] = W4[t + i * 256];

    const int c4 = t & 31;
    const int r4 = t >> 5;

    for (int sub = 0; sub < 4; ++sub) {
        const int r0 = (blockIdx.x * 4 + sub) * 32;
        if (r0 >= N) break;          // N % 32 == 0 (40000)
        __syncthreads();             // Hl reuse fence; covers W staging on sub==0
        const float4* H4 = (const float4*)(h + (size_t)r0 * 128);
#pragma unroll
        for (int i = 0; i < 4; ++i) Hl[t + i * 256] = H4[t + i * 256];
        __syncthreads();

        float4 acc0 = make_float4(0.f, 0.f, 0.f, 0.f);
        float4 acc1 = acc0, acc2 = acc0, acc3 = acc0;
#pragma unroll 8
        for (int k4 = 0; k4 < 32; ++k4) {
            float4 b0 = Wl[(k4 * 4 + 0) * 32 + c4];
            float4 b1 = Wl[(k4 * 4 + 1) * 32 + c4];
            float4 b2 = Wl[(k4 * 4 + 2) * 32 + c4];
            float4 b3 = Wl[(k4 * 4 + 3) * 32 + c4];
            float4 a0 = Hl[(r4 * 4 + 0) * 32 + k4];
            float4 a1 = Hl[(r4 * 4 + 1) * 32 + k4];
            float4 a2 = Hl[(r4 * 4 + 2) * 32 + k4];
            float4 a3 = Hl[(r4 * 4 + 3) * 32 + k4];
            FMA4(acc0, a0.x, b0); FMA4(acc0, a0.y, b1); FMA4(acc0, a0.z, b2); FMA4(acc0, a0.w, b3);
            FMA4(acc1, a1.x, b0); FMA4(acc1, a1.y, b1); FMA4(acc1, a1.z, b2); FMA4(acc1, a1.w, b3);
            FMA4(acc2, a2.x, b0); FMA4(acc2, a2.y, b1); FMA4(acc2, a2.z, b2); FMA4(acc2, a2.w, b3);
            FMA4(acc3, a3.x, b0); FMA4(acc3, a3.y, b1); FMA4(acc3, a3.z, b2); FMA4(acc3, a3.w, b3);
        }
        const int row = r0 + r4 * 4;
        float4* O = (float4*)Osel;
        O[(size_t)(row + 0) * 32 + c4] = acc0;
        O[(size_t)(row + 1) * 32 + c4] = acc1;
        O[(size_t)(row + 2) * 32 + c4] = acc2;
        O[(size_t)(row + 3) * 32 + c4] = acc3;
    }
}

// -------------------------- CSR build (stable by dst) ----------------------
__global__ __launch_bounds__(256) void count_deg(
    const int* __restrict__ dst, int* __restrict__ deg, int E)
{
    const int e = blockIdx.x * 256 + threadIdx.x;
    if (e < E) atomicAdd(&deg[dst[e]], 1);
}

// Hierarchical scan, step 1: per-256-chunk sums via wave shuffle reduce.
__global__ __launch_bounds__(256) void chunk_reduce(
    const int* __restrict__ deg, int* __restrict__ csum, int N)
{
    const int t = threadIdx.x;
    const int i = blockIdx.x * 256 + t;
    int x = (i < N) ? deg[i] : 0;
#pragma unroll
    for (int off = 32; off; off >>= 1) x += __shfl_down(x, off, 64);
    __shared__ int ws[4];
    if ((t & 63) == 0) ws[t >> 6] = x;
    __syncthreads();
    if (t == 0) csum[blockIdx.x] = ws[0] + ws[1] + ws[2] + ws[3];
}

// Step 2: exclusive scan of chunk sums (nChunks <= 256 per pass; carry loop
// for generality). Single small block -- input is only nChunks ints.
__global__ __launch_bounds__(256) void scan_chunks(
    const int* __restrict__ csum, int* __restrict__ coff, int nChunks)
{
    __shared__ int s[256];
    __shared__ int carry;
    const int t = threadIdx.x;
    if (t == 0) carry = 0;
    __syncthreads();
    for (int base = 0; base < nChunks; base += 256) {
        const int i = base + t;
        int x = (i < nChunks) ? csum[i] : 0;
        s[t] = x;
        __syncthreads();
        for (int off = 1; off < 256; off <<= 1) {
            int v = (t >= off) ? s[t - off] : 0;
            __syncthreads();
            s[t] += v;
            __syncthreads();
        }
        if (i < nChunks) coff[i] = carry + s[t] - x;  // exclusive
        __syncthreads();
        if (t == 0) carry += s[255];
        __syncthreads();
    }
}

// Step 3: per-chunk inclusive scan + chunk offset -> rowptr.
__global__ __launch_bounds__(256) void chunk_scan(
    const int* __restrict__ deg, const int* __restrict__ coff,
    int* __restrict__ rowptr, int N)
{
    __shared__ int s[256];
    const int t = threadIdx.x;
    const int i = blockIdx.x * 256 + t;
    int x = (i < N) ? deg[i] : 0;
    s[t] = x;
    __syncthreads();
    for (int off = 1; off < 256; off <<= 1) {
        int v = (t >= off) ? s[t - off] : 0;
        __syncthreads();
        s[t] += v;
        __syncthreads();
    }
    if (i < N) rowptr[i + 1] = coff[blockIdx.x] + s[t];
    if (i == 0) rowptr[0] = 0;
}

__global__ __launch_bounds__(256) void scatter_eids(
    const int* __restrict__ dst, const int* __restrict__ rowptr,
    int* __restrict__ cur, int* __restrict__ eids, int E)
{
    const int e = blockIdx.x * 256 + threadIdx.x;
    if (e >= E) return;
    const int d = dst[e];
    const int pos = rowptr[d] + atomicAdd(&cur[d], 1);
    eids[pos] = e;
}

// Per-dst ascending edge ids (deg ~ Poisson(16): insertion sort is cheap).
__global__ __launch_bounds__(256) void sort_lists(
    const int* __restrict__ rowptr, int* __restrict__ eids, int N)
{
    const int n = blockIdx.x * 256 + threadIdx.x;
    if (n >= N) return;
    const int lo = rowptr[n], hi = rowptr[n + 1];
    for (int i = lo + 1; i < hi; ++i) {
        const int key = eids[i];
        int j = i - 1;
        while (j >= lo && eids[j] > key) { eids[j + 1] = eids[j]; --j; }
        eids[j + 1] = key;
    }
}

// ------------------- np.add.at-order fp32 edge accumulation ----------------
// FROZEN arithmetic: sequential fp32 adds, ascending edge order, contract off.
__global__ __launch_bounds__(128) void attn_out(
    const int* __restrict__ src, const int* __restrict__ rowptr,
    const int* __restrict__ eids,
    const float* __restrict__ Kf, const float* __restrict__ Qf,
    const float* __restrict__ Vf,
    float* __restrict__ out, int N)
{
#pragma clang fp contract(off)
    const int d = blockIdx.x;
    const int c = threadIdx.x;
    const float q = Qf[(size_t)d * 128 + c];
    const int lo = rowptr[d], hi = rowptr[d + 1];
    float z = 0.f, wv = 0.f;
    for (int i = lo; i < hi; ++i) {
        const int e = eids[i];
        const int s = src[e];
        const float k = Kf[(size_t)s * 128 + c];
        const float v = Vf[(size_t)s * 128 + c];
        const float sc = (k * q) * 0.25f;  // f32(K*Q) * inv_sqrt_d (exact x0.25)
        z = z + sc;                        // np.add.at rounding, edge order
        const float p = v * sc;            // f32(V*score)
        wv = wv + p;
    }
    out[(size_t)d * 128 + c] = wv / (z + 1e-6f);
}

extern "C" void kernel_launch(void* const* d_in, const int* in_sizes, int n_in,
                              void* d_out, int out_size, void* d_ws, size_t ws_size,
                              hipStream_t stream)
{
    const float* h  = (const float*)d_in[0];
    const int* src  = (const int*)d_in[1];
    const int* dst  = (const int*)d_in[2];
    const float* WQ = (const float*)d_in[3];
    const float* WK = (const float*)d_in[4];
    const float* WV = (const float*)d_in[5];
    const int N = in_sizes[0] / 128;   // 40000
    const int E = in_sizes[1];         // 640000
    const size_t NC = (size_t)N * 128;
    const int nChunks = (N + 255) / 256;

    // Workspace (~65 MB): Kf,Qf,Vf f32; deg,cur,rowptr,eids,csum,coff int.
    float* Kf = (float*)d_ws;
    float* Qf = Kf + NC;
    float* Vf = Qf + NC;
    int* deg    = (int*)(Vf + NC);
    int* cur    = deg + N;
    int* rowptr = cur + N;         // N+1 entries
    int* eids   = rowptr + (N + 1);
    int* csum   = eids + E;
    int* coff   = csum + nChunks;
    float* outp = (float*)d_out;

    hipMemsetAsync(deg, 0, (size_t)2 * N * sizeof(int), stream);  // deg + cur

    dim3 ggrid((N + 127) / 128, 3);
    gemm_qkv<<<ggrid, 256, 0, stream>>>(h, WQ, WK, WV, Qf, Kf, Vf, N);

    const int eb = (E + 255) / 256;
    count_deg<<<eb, 256, 0, stream>>>(dst, deg, E);
    chunk_reduce<<<nChunks, 256, 0, stream>>>(deg, csum, N);
    scan_chunks<<<1, 256, 0, stream>>>(csum, coff, nChunks);
    chunk_scan<<<nChunks, 256, 0, stream>>>(deg, coff, rowptr, N);
    scatter_eids<<<eb, 256, 0, stream>>>(dst, rowptr, cur, eids, E);
    sort_lists<<<(N + 255) / 256, 256, 0, stream>>>(rowptr, eids, N);

    attn_out<<<N, 128, 0, stream>>>(src, rowptr, eids, Kf, Qf, Vf, outp, N);
}

// Round 7
// 336.211 us; speedup vs baseline: 1.5171x; 1.0411x over previous
//
#include <hip/hip_runtime.h>

// PASSED with absmax = 0.0 (bitwise match vs np reference).
// FROZEN: all fp arithmetic (gemm accumulation order; attn per-edge ops and
// per-(dst,channel) ascending-edge summation order). Integer/layout/scheduling
// changes only.
// R6: attn_out was HBM-bound at 47% BW (dependent-chain gather). This round:
//  (a) pre-gathered srcs[] (kills eids->src indirection),
//  (b) K|V interleaved per-node 1KB rows (one contiguous gather region),
//  (c) wave-per-dst, float2/thread, unroll-4 load-first (8 loads in flight).

#define FMA4(acc, s, b) do { \
    (acc).x = fmaf((s), (b).x, (acc).x); \
    (acc).y = fmaf((s), (b).y, (acc).y); \
    (acc).z = fmaf((s), (b).z, (acc).z); \
    (acc).w = fmaf((s), (b).w, (acc).w); } while (0)

// ---------------------------------------------------------------------------
// fp32 GEMM (arithmetic frozen). which=0 -> Qf[n][128]; which=1 -> K half of
// KV[n][256]; which=2 -> V half of KV[n][256]. Only store addresses differ.
// ---------------------------------------------------------------------------
__global__ __launch_bounds__(256) void gemm_qkv(
    const float* __restrict__ h,
    const float* __restrict__ WQ,
    const float* __restrict__ WK,
    const float* __restrict__ WV,
    float* __restrict__ Qf,
    float* __restrict__ KV,
    int N)
{
    __shared__ float4 Wl[128 * 32];  // [k][c4]  64 KB
    __shared__ float4 Hl[32 * 32];   // [row][k4] 16 KB
    const int t = threadIdx.x;
    const int which = blockIdx.y;
    const float* Wsel = (which == 0) ? WQ : ((which == 1) ? WK : WV);
    const float4* W4 = (const float4*)Wsel;
#pragma unroll
    for (int i = 0; i < 16; ++i) Wl[t + i * 256] = W4[t + i * 256];

    const int c4 = t & 31;
    const int r4 = t >> 5;
    // Output addressing: Q rows stride 32 float4; KV rows stride 64 float4,
    // V half offset +32.
    float4* Obase = (which == 0) ? (float4*)Qf : (float4*)KV;
    const int ostride = (which == 0) ? 32 : 64;
    const int ooff = (which == 2) ? 32 : 0;

    for (int sub = 0; sub < 4; ++sub) {
        const int r0 = (blockIdx.x * 4 + sub) * 32;
        if (r0 >= N) break;          // N % 32 == 0 (40000)
        __syncthreads();             // Hl reuse fence; covers W staging on sub==0
        const float4* H4 = (const float4*)(h + (size_t)r0 * 128);
#pragma unroll
        for (int i = 0; i < 4; ++i) Hl[t + i * 256] = H4[t + i * 256];
        __syncthreads();

        float4 acc0 = make_float4(0.f, 0.f, 0.f, 0.f);
        float4 acc1 = acc0, acc2 = acc0, acc3 = acc0;
#pragma unroll 8
        for (int k4 = 0; k4 < 32; ++k4) {
            float4 b0 = Wl[(k4 * 4 + 0) * 32 + c4];
            float4 b1 = Wl[(k4 * 4 + 1) * 32 + c4];
            float4 b2 = Wl[(k4 * 4 + 2) * 32 + c4];
            float4 b3 = Wl[(k4 * 4 + 3) * 32 + c4];
            float4 a0 = Hl[(r4 * 4 + 0) * 32 + k4];
            float4 a1 = Hl[(r4 * 4 + 1) * 32 + k4];
            float4 a2 = Hl[(r4 * 4 + 2) * 32 + k4];
            float4 a3 = Hl[(r4 * 4 + 3) * 32 + k4];
            FMA4(acc0, a0.x, b0); FMA4(acc0, a0.y, b1); FMA4(acc0, a0.z, b2); FMA4(acc0, a0.w, b3);
            FMA4(acc1, a1.x, b0); FMA4(acc1, a1.y, b1); FMA4(acc1, a1.z, b2); FMA4(acc1, a1.w, b3);
            FMA4(acc2, a2.x, b0); FMA4(acc2, a2.y, b1); FMA4(acc2, a2.z, b2); FMA4(acc2, a2.w, b3);
            FMA4(acc3, a3.x, b0); FMA4(acc3, a3.y, b1); FMA4(acc3, a3.z, b2); FMA4(acc3, a3.w, b3);
        }
        const int row = r0 + r4 * 4;
        Obase[(size_t)(row + 0) * ostride + ooff + c4] = acc0;
        Obase[(size_t)(row + 1) * ostride + ooff + c4] = acc1;
        Obase[(size_t)(row + 2) * ostride + ooff + c4] = acc2;
        Obase[(size_t)(row + 3) * ostride + ooff + c4] = acc3;
    }
}

// -------------------------- CSR build (stable by dst) ----------------------
__global__ __launch_bounds__(256) void count_deg(
    const int* __restrict__ dst, int* __restrict__ deg, int E)
{
    const int e = blockIdx.x * 256 + threadIdx.x;
    if (e < E) atomicAdd(&deg[dst[e]], 1);
}

__global__ __launch_bounds__(256) void chunk_reduce(
    const int* __restrict__ deg, int* __restrict__ csum, int N)
{
    const int t = threadIdx.x;
    const int i = blockIdx.x * 256 + t;
    int x = (i < N) ? deg[i] : 0;
#pragma unroll
    for (int off = 32; off; off >>= 1) x += __shfl_down(x, off, 64);
    __shared__ int ws[4];
    if ((t & 63) == 0) ws[t >> 6] = x;
    __syncthreads();
    if (t == 0) csum[blockIdx.x] = ws[0] + ws[1] + ws[2] + ws[3];
}

__global__ __launch_bounds__(256) void scan_chunks(
    const int* __restrict__ csum, int* __restrict__ coff, int nChunks)
{
    __shared__ int s[256];
    __shared__ int carry;
    const int t = threadIdx.x;
    if (t == 0) carry = 0;
    __syncthreads();
    for (int base = 0; base < nChunks; base += 256) {
        const int i = base + t;
        int x = (i < nChunks) ? csum[i] : 0;
        s[t] = x;
        __syncthreads();
        for (int off = 1; off < 256; off <<= 1) {
            int v = (t >= off) ? s[t - off] : 0;
            __syncthreads();
            s[t] += v;
            __syncthreads();
        }
        if (i < nChunks) coff[i] = carry + s[t] - x;  // exclusive
        __syncthreads();
        if (t == 0) carry += s[255];
        __syncthreads();
    }
}

__global__ __launch_bounds__(256) void chunk_scan(
    const int* __restrict__ deg, const int* __restrict__ coff,
    int* __restrict__ rowptr, int N)
{
    __shared__ int s[256];
    const int t = threadIdx.x;
    const int i = blockIdx.x * 256 + t;
    int x = (i < N) ? deg[i] : 0;
    s[t] = x;
    __syncthreads();
    for (int off = 1; off < 256; off <<= 1) {
        int v = (t >= off) ? s[t - off] : 0;
        __syncthreads();
        s[t] += v;
        __syncthreads();
    }
    if (i < N) rowptr[i + 1] = coff[blockIdx.x] + s[t];
    if (i == 0) rowptr[0] = 0;
}

// Scatter (eid, src) pairs via atomic ticket (unstable order, fixed by sort).
__global__ __launch_bounds__(256) void scatter_pairs(
    const int* __restrict__ dst, const int* __restrict__ src,
    const int* __restrict__ rowptr, int* __restrict__ cur,
    int2* __restrict__ pairs, int E)
{
    const int e = blockIdx.x * 256 + threadIdx.x;
    if (e >= E) return;
    const int d = dst[e];
    const int pos = rowptr[d] + atomicAdd(&cur[d], 1);
    pairs[pos] = make_int2(e, src[e]);
}

// Per-dst insertion sort by eid (deg ~ Poisson(16)), then emit srcs[] in
// CSR order -> attn needs no eids->src indirection.
__global__ __launch_bounds__(256) void sort_emit_srcs(
    const int* __restrict__ rowptr, int2* __restrict__ pairs,
    int* __restrict__ srcs, int N)
{
    const int n = blockIdx.x * 256 + threadIdx.x;
    if (n >= N) return;
    const int lo = rowptr[n], hi = rowptr[n + 1];
    for (int i = lo + 1; i < hi; ++i) {
        const int2 key = pairs[i];
        int j = i - 1;
        while (j >= lo && pairs[j].x > key.x) { pairs[j + 1] = pairs[j]; --j; }
        pairs[j + 1] = key;
    }
    for (int i = lo; i < hi; ++i) srcs[i] = pairs[i].y;
}

// ------------------- np.add.at-order fp32 edge accumulation ----------------
// FROZEN arithmetic per channel: sc = (k*q)*0.25f; z += sc; wv += v*sc, edges
// ascending. One wave per dst, thread c owns channels {2c, 2c+1}. Unroll-4
// with all loads issued before the ordered adds (loads are order-free).
__global__ __launch_bounds__(64) void attn_out(
    const int* __restrict__ srcs, const int* __restrict__ rowptr,
    const float* __restrict__ KV, const float* __restrict__ Qf,
    float* __restrict__ out, int N)
{
#pragma clang fp contract(off)
    const int d = blockIdx.x;
    const int c = threadIdx.x;  // 0..63
    const float2 q = ((const float2*)Qf)[(size_t)d * 64 + c];
    const int lo = rowptr[d], hi = rowptr[d + 1];
    const float2* KV2 = (const float2*)KV;
    float2 z = make_float2(0.f, 0.f), wv = z;

#define EDGE_UPD(k, v) do { \
        float sc0 = ((k).x * q.x) * 0.25f; z.x = z.x + sc0; wv.x = wv.x + (v).x * sc0; \
        float sc1 = ((k).y * q.y) * 0.25f; z.y = z.y + sc1; wv.y = wv.y + (v).y * sc1; \
    } while (0)

    int i = lo;
    for (; i + 4 <= hi; i += 4) {
        const int s0 = srcs[i + 0], s1 = srcs[i + 1];
        const int s2 = srcs[i + 2], s3 = srcs[i + 3];
        const float2 k0 = KV2[(size_t)s0 * 128 + c], v0 = KV2[(size_t)s0 * 128 + 64 + c];
        const float2 k1 = KV2[(size_t)s1 * 128 + c], v1 = KV2[(size_t)s1 * 128 + 64 + c];
        const float2 k2 = KV2[(size_t)s2 * 128 + c], v2 = KV2[(size_t)s2 * 128 + 64 + c];
        const float2 k3 = KV2[(size_t)s3 * 128 + c], v3 = KV2[(size_t)s3 * 128 + 64 + c];
        EDGE_UPD(k0, v0); EDGE_UPD(k1, v1); EDGE_UPD(k2, v2); EDGE_UPD(k3, v3);
    }
    for (; i < hi; ++i) {
        const int s = srcs[i];
        const float2 k = KV2[(size_t)s * 128 + c], v = KV2[(size_t)s * 128 + 64 + c];
        EDGE_UPD(k, v);
    }
#undef EDGE_UPD

    float2 o;
    o.x = wv.x / (z.x + 1e-6f);
    o.y = wv.y / (z.y + 1e-6f);
    ((float2*)out)[(size_t)d * 64 + c] = o;
}

extern "C" void kernel_launch(void* const* d_in, const int* in_sizes, int n_in,
                              void* d_out, int out_size, void* d_ws, size_t ws_size,
                              hipStream_t stream)
{
    const float* h  = (const float*)d_in[0];
    const int* src  = (const int*)d_in[1];
    const int* dst  = (const int*)d_in[2];
    const float* WQ = (const float*)d_in[3];
    const float* WK = (const float*)d_in[4];
    const float* WV = (const float*)d_in[5];
    const int N = in_sizes[0] / 128;   // 40000
    const int E = in_sizes[1];         // 640000
    const size_t NC = (size_t)N * 128;
    const int nChunks = (N + 255) / 256;

    // Workspace (~80 MB): KV f32[N][256], Qf f32[N][128], ints.
    float* KV = (float*)d_ws;          // 41 MB
    float* Qf = KV + (size_t)N * 256;  // 20.5 MB
    int* deg    = (int*)(Qf + NC);
    int* cur    = deg + N;
    int* rowptr = cur + N;             // N+1
    int* csum   = rowptr + (N + 1);
    int* coff   = csum + nChunks;
    int* srcs   = coff + nChunks;      // E
    int2* pairs = (int2*)(srcs + E);   // E int2 (8B-aligned: offset even ints)
    float* outp = (float*)d_out;

    hipMemsetAsync(deg, 0, (size_t)2 * N * sizeof(int), stream);  // deg + cur

    dim3 ggrid((N + 127) / 128, 3);
    gemm_qkv<<<ggrid, 256, 0, stream>>>(h, WQ, WK, WV, Qf, KV, N);

    const int eb = (E + 255) / 256;
    count_deg<<<eb, 256, 0, stream>>>(dst, deg, E);
    chunk_reduce<<<nChunks, 256, 0, stream>>>(deg, csum, N);
    scan_chunks<<<1, 256, 0, stream>>>(csum, coff, nChunks);
    chunk_scan<<<nChunks, 256, 0, stream>>>(deg, coff, rowptr, N);
    scatter_pairs<<<eb, 256, 0, stream>>>(dst, src, rowptr, cur, pairs, E);
    sort_emit_srcs<<<(N + 255) / 256, 256, 0, stream>>>(rowptr, pairs, srcs, N);

    attn_out<<<N, 64, 0, stream>>>(srcs, rowptr, KV, Qf, outp, N);
}

// Round 9
// 302.065 us; speedup vs baseline: 1.6886x; 1.1130x over previous
//
#include <hip/hip_runtime.h>

// PASSED with absmax = 0.0 (bitwise match vs np reference).
// FROZEN: all fp arithmetic (per-element gemm fmaf chain, k ascending;
// attn per-edge ops and per-(dst,channel) ascending-edge-id summation).
// Integer/layout/scheduling changes only.
// R7: (1) gemm retiled 8x8/thread (same per-element chain, 4x fewer LDS reads
// per FMA); (2) serial insertion sort -> wave-parallel rank via shfl;
// (3) attn: 2 waves/block + unroll-8 (more WG-slot occupancy, 16 loads in
// flight).

#define FMA4(acc, s, b) do { \
    (acc).x = fmaf((s), (b).x, (acc).x); \
    (acc).y = fmaf((s), (b).y, (acc).y); \
    (acc).z = fmaf((s), (b).z, (acc).z); \
    (acc).w = fmaf((s), (b).w, (acc).w); } while (0)

// ---------------------------------------------------------------------------
// fp32 GEMM, 128x128 tile per block, 8x8 per thread, K in 4 chunks of 32.
// which=0 -> Qf[n][128]; which=1 -> K half of KV[n][256]; which=2 -> V half.
// Per-output-element arithmetic: single accumulator, fmaf, k=0..127 ascending
// (kc outer, k4 middle, kk inner) == previous kernel == BLAS order. FROZEN.
// ---------------------------------------------------------------------------
__global__ __launch_bounds__(256) void gemm_qkv(
    const float* __restrict__ h,
    const float* __restrict__ WQ,
    const float* __restrict__ WK,
    const float* __restrict__ WV,
    float* __restrict__ Qf,
    float* __restrict__ KV,
    int N)
{
    __shared__ float4 Wl[32 * 32];   // [k][c4]   16 KB (one K-chunk)
    __shared__ float4 Hl[128 * 8];   // [row][k4] 16 KB (one K-chunk)
    const int t = threadIdx.x;
    const int which = blockIdx.y;
    const float* Wsel = (which == 0) ? WQ : ((which == 1) ? WK : WV);
    const float4* W4 = (const float4*)Wsel;
    const int r0 = blockIdx.x * 128;

    const int tc = t & 15;   // col group: float4 cols tc*2, tc*2+1 (8 cols)
    const int tr = t >> 4;   // row group: rows tr*8 .. tr*8+7

    float4 acc[8][2];
#pragma unroll
    for (int i = 0; i < 8; ++i) {
        acc[i][0] = make_float4(0.f, 0.f, 0.f, 0.f);
        acc[i][1] = make_float4(0.f, 0.f, 0.f, 0.f);
    }

    for (int kc = 0; kc < 4; ++kc) {
        __syncthreads();   // protect previous chunk's reads
#pragma unroll
        for (int i = 0; i < 4; ++i) {           // Wl: 32 k-rows x 32 float4
            const int idx = t + i * 256;
            const int k = idx >> 5, c = idx & 31;
            Wl[idx] = W4[(size_t)(kc * 32 + k) * 32 + c];
        }
#pragma unroll
        for (int i = 0; i < 4; ++i) {           // Hl: 128 rows x 8 float4
            const int idx = t + i * 256;
            const int row = idx >> 3, kk = idx & 7;
            float4 v = make_float4(0.f, 0.f, 0.f, 0.f);
            if (r0 + row < N)
                v = ((const float4*)h)[(size_t)(r0 + row) * 32 + kc * 8 + kk];
            Hl[row * 8 + kk] = v;
        }
        __syncthreads();

        for (int k4 = 0; k4 < 8; ++k4) {
            const float4 b0a = Wl[(k4 * 4 + 0) * 32 + tc * 2];
            const float4 b0b = Wl[(k4 * 4 + 0) * 32 + tc * 2 + 1];
            const float4 b1a = Wl[(k4 * 4 + 1) * 32 + tc * 2];
            const float4 b1b = Wl[(k4 * 4 + 1) * 32 + tc * 2 + 1];
            const float4 b2a = Wl[(k4 * 4 + 2) * 32 + tc * 2];
            const float4 b2b = Wl[(k4 * 4 + 2) * 32 + tc * 2 + 1];
            const float4 b3a = Wl[(k4 * 4 + 3) * 32 + tc * 2];
            const float4 b3b = Wl[(k4 * 4 + 3) * 32 + tc * 2 + 1];
#pragma unroll
            for (int r = 0; r < 8; ++r) {
                const float4 a = Hl[(tr * 8 + r) * 8 + k4];
                // per-element k order: kk = 0,1,2,3 (a.x,a.y,a.z,a.w)
                FMA4(acc[r][0], a.x, b0a); FMA4(acc[r][1], a.x, b0b);
                FMA4(acc[r][0], a.y, b1a); FMA4(acc[r][1], a.y, b1b);
                FMA4(acc[r][0], a.z, b2a); FMA4(acc[r][1], a.z, b2b);
                FMA4(acc[r][0], a.w, b3a); FMA4(acc[r][1], a.w, b3b);
            }
        }
    }

    // store: Q rows stride 32 float4; KV rows stride 64, V half offset +32.
    float4* Obase = (which == 0) ? (float4*)Qf : (float4*)KV;
    const int ostride = (which == 0) ? 32 : 64;
    const int ooff = (which == 2) ? 32 : 0;
#pragma unroll
    for (int r = 0; r < 8; ++r) {
        const int row = r0 + tr * 8 + r;
        if (row < N) {
            Obase[(size_t)row * ostride + ooff + tc * 2]     = acc[r][0];
            Obase[(size_t)row * ostride + ooff + tc * 2 + 1] = acc[r][1];
        }
    }
}

// -------------------------- CSR build (stable by dst) ----------------------
__global__ __launch_bounds__(256) void count_deg(
    const int* __restrict__ dst, int* __restrict__ deg, int E)
{
    const int e = blockIdx.x * 256 + threadIdx.x;
    if (e < E) atomicAdd(&deg[dst[e]], 1);
}

__global__ __launch_bounds__(256) void chunk_reduce(
    const int* __restrict__ deg, int* __restrict__ csum, int N)
{
    const int t = threadIdx.x;
    const int i = blockIdx.x * 256 + t;
    int x = (i < N) ? deg[i] : 0;
#pragma unroll
    for (int off = 32; off; off >>= 1) x += __shfl_down(x, off, 64);
    __shared__ int ws[4];
    if ((t & 63) == 0) ws[t >> 6] = x;
    __syncthreads();
    if (t == 0) csum[blockIdx.x] = ws[0] + ws[1] + ws[2] + ws[3];
}

__global__ __launch_bounds__(256) void scan_chunks(
    const int* __restrict__ csum, int* __restrict__ coff, int nChunks)
{
    __shared__ int s[256];
    __shared__ int carry;
    const int t = threadIdx.x;
    if (t == 0) carry = 0;
    __syncthreads();
    for (int base = 0; base < nChunks; base += 256) {
        const int i = base + t;
        int x = (i < nChunks) ? csum[i] : 0;
        s[t] = x;
        __syncthreads();
        for (int off = 1; off < 256; off <<= 1) {
            int v = (t >= off) ? s[t - off] : 0;
            __syncthreads();
            s[t] += v;
            __syncthreads();
        }
        if (i < nChunks) coff[i] = carry + s[t] - x;  // exclusive
        __syncthreads();
        if (t == 0) carry += s[255];
        __syncthreads();
    }
}

__global__ __launch_bounds__(256) void chunk_scan(
    const int* __restrict__ deg, const int* __restrict__ coff,
    int* __restrict__ rowptr, int N)
{
    __shared__ int s[256];
    const int t = threadIdx.x;
    const int i = blockIdx.x * 256 + t;
    int x = (i < N) ? deg[i] : 0;
    s[t] = x;
    __syncthreads();
    for (int off = 1; off < 256; off <<= 1) {
        int v = (t >= off) ? s[t - off] : 0;
        __syncthreads();
        s[t] += v;
        __syncthreads();
    }
    if (i < N) rowptr[i + 1] = coff[blockIdx.x] + s[t];
    if (i == 0) rowptr[0] = 0;
}

// Scatter (eid, src) pairs via atomic ticket (arrival order; rank fixes it).
__global__ __launch_bounds__(256) void scatter_pairs(
    const int* __restrict__ dst, const int* __restrict__ src,
    const int* __restrict__ rowptr, int* __restrict__ cur,
    int2* __restrict__ pairs, int E)
{
    const int e = blockIdx.x * 256 + threadIdx.x;
    if (e >= E) return;
    const int d = dst[e];
    const int pos = rowptr[d] + atomicAdd(&cur[d], 1);
    pairs[pos] = make_int2(e, src[e]);
}

// Wave-parallel stable ordering: rank(e) = #{e' in same dst : eid' < eid}.
// One wave per dst (4 waves/block). Emits srcs[] in ascending-eid order ==
// np.add.at order. deg > 64 falls back to a serial path (P ~ 0 for this dist).
__global__ __launch_bounds__(256) void rank_emit(
    const int* __restrict__ rowptr, const int2* __restrict__ pairs,
    int* __restrict__ srcs, int N)
{
    const int wave = threadIdx.x >> 6;
    const int lane = threadIdx.x & 63;
    const int d = blockIdx.x * 4 + wave;
    if (d >= N) return;
    const int lo = rowptr[d];
    const int deg = rowptr[d + 1] - lo;
    if (deg <= 64) {
        int2 p = make_int2(0x7fffffff, 0);
        if (lane < deg) p = pairs[lo + lane];
        int rank = 0;
        for (int j = 0; j < deg; ++j) {
            const int kj = __shfl(p.x, j, 64);
            rank += (kj < p.x) ? 1 : 0;
        }
        if (lane < deg) srcs[lo + rank] = p.y;
    } else if (lane == 0) {
        for (int i = 0; i < deg; ++i) {
            const int2 pi = pairs[lo + i];
            int rank = 0;
            for (int j = 0; j < deg; ++j) rank += (pairs[lo + j].x < pi.x) ? 1 : 0;
            srcs[lo + rank] = pi.y;
        }
    }
}

// ------------------- np.add.at-order fp32 edge accumulation ----------------
// FROZEN per channel: sc = (k*q)*0.25f; z += sc; wv += v*sc, edges ascending.
// One wave per dst (2 waves/block for WG-slot occupancy); thread owns channels
// {2c,2c+1}; unroll-8 with loads batched before the ordered adds.
__global__ __launch_bounds__(128) void attn_out(
    const int* __restrict__ srcs, const int* __restrict__ rowptr,
    const float* __restrict__ KV, const float* __restrict__ Qf,
    float* __restrict__ out, int N)
{
#pragma clang fp contract(off)
    const int wave = threadIdx.x >> 6;
    const int lane = threadIdx.x & 63;
    const int d = blockIdx.x * 2 + wave;
    if (d >= N) return;
    const float2 q = ((const float2*)Qf)[(size_t)d * 64 + lane];
    const int lo = rowptr[d], hi = rowptr[d + 1];
    const float2* KV2 = (const float2*)KV;
    float2 z = make_float2(0.f, 0.f), wv = z;

#define EDGE_UPD(k, v) do { \
        float sc0 = ((k).x * q.x) * 0.25f; z.x = z.x + sc0; wv.x = wv.x + (v).x * sc0; \
        float sc1 = ((k).y * q.y) * 0.25f; z.y = z.y + sc1; wv.y = wv.y + (v).y * sc1; \
    } while (0)

    int i = lo;
    for (; i + 8 <= hi; i += 8) {
        int s[8];
#pragma unroll
        for (int u = 0; u < 8; ++u) s[u] = srcs[i + u];
        float2 kk[8], vv[8];
#pragma unroll
        for (int u = 0; u < 8; ++u) {
            kk[u] = KV2[(size_t)s[u] * 128 + lane];
            vv[u] = KV2[(size_t)s[u] * 128 + 64 + lane];
        }
#pragma unroll
        for (int u = 0; u < 8; ++u) EDGE_UPD(kk[u], vv[u]);
    }
    for (; i + 4 <= hi; i += 4) {
        const int s0 = srcs[i + 0], s1 = srcs[i + 1];
        const int s2 = srcs[i + 2], s3 = srcs[i + 3];
        const float2 k0 = KV2[(size_t)s0 * 128 + lane], v0 = KV2[(size_t)s0 * 128 + 64 + lane];
        const float2 k1 = KV2[(size_t)s1 * 128 + lane], v1 = KV2[(size_t)s1 * 128 + 64 + lane];
        const float2 k2 = KV2[(size_t)s2 * 128 + lane], v2 = KV2[(size_t)s2 * 128 + 64 + lane];
        const float2 k3 = KV2[(size_t)s3 * 128 + lane], v3 = KV2[(size_t)s3 * 128 + 64 + lane];
        EDGE_UPD(k0, v0); EDGE_UPD(k1, v1); EDGE_UPD(k2, v2); EDGE_UPD(k3, v3);
    }
    for (; i < hi; ++i) {
        const int s = srcs[i];
        const float2 k = KV2[(size_t)s * 128 + lane], v = KV2[(size_t)s * 128 + 64 + lane];
        EDGE_UPD(k, v);
    }
#undef EDGE_UPD

    float2 o;
    o.x = wv.x / (z.x + 1e-6f);
    o.y = wv.y / (z.y + 1e-6f);
    ((float2*)out)[(size_t)d * 64 + lane] = o;
}

extern "C" void kernel_launch(void* const* d_in, const int* in_sizes, int n_in,
                              void* d_out, int out_size, void* d_ws, size_t ws_size,
                              hipStream_t stream)
{
    const float* h  = (const float*)d_in[0];
    const int* src  = (const int*)d_in[1];
    const int* dst  = (const int*)d_in[2];
    const float* WQ = (const float*)d_in[3];
    const float* WK = (const float*)d_in[4];
    const float* WV = (const float*)d_in[5];
    const int N = in_sizes[0] / 128;   // 40000
    const int E = in_sizes[1];         // 640000
    const size_t NC = (size_t)N * 128;
    const int nChunks = (N + 255) / 256;

    // Workspace (~80 MB). rowptr padded to N+2 so `pairs` stays 8B-aligned.
    float* KV = (float*)d_ws;          // N*256 f32
    float* Qf = KV + (size_t)N * 256;  // N*128 f32
    int* deg    = (int*)(Qf + NC);     // N
    int* cur    = deg + N;             // N
    int* rowptr = cur + N;             // N+2 (padded)
    int* csum   = rowptr + (N + 2);    // nChunks
    int* coff   = csum + nChunks;      // nChunks  (157+157 = even)
    int* srcs   = coff + nChunks;      // E (even)
    int2* pairs = (int2*)(srcs + E);   // E int2, 8B-aligned
    float* outp = (float*)d_out;

    hipMemsetAsync(deg, 0, (size_t)2 * N * sizeof(int), stream);  // deg + cur

    dim3 ggrid((N + 127) / 128, 3);
    gemm_qkv<<<ggrid, 256, 0, stream>>>(h, WQ, WK, WV, Qf, KV, N);

    const int eb = (E + 255) / 256;
    count_deg<<<eb, 256, 0, stream>>>(dst, deg, E);
    chunk_reduce<<<nChunks, 256, 0, stream>>>(deg, csum, N);
    scan_chunks<<<1, 256, 0, stream>>>(csum, coff, nChunks);
    chunk_scan<<<nChunks, 256, 0, stream>>>(deg, coff, rowptr, N);
    scatter_pairs<<<eb, 256, 0, stream>>>(dst, src, rowptr, cur, pairs, E);
    rank_emit<<<(N + 3) / 4, 256, 0, stream>>>(rowptr, pairs, srcs, N);

    attn_out<<<(N + 1) / 2, 128, 0, stream>>>(srcs, rowptr, KV, Qf, outp, N);
}

// Round 10
// 294.801 us; speedup vs baseline: 1.7302x; 1.0246x over previous
//
#include <hip/hip_runtime.h>

// PASSED with absmax = 0.0 (bitwise match vs np reference).
// FROZEN: all fp arithmetic (per-element gemm fmaf chain, k ascending;
// attn per-edge ops and per-(dst,channel) ascending-edge-id summation).
// Integer/layout/scheduling changes only.
// R9: (1) gemm LDS de-conflict: W-cols split tc/tc+16 (2-way, free) + Hl
// XOR swizzle (4-way -> conflict-free); (2) attn srcs prefetch (hide the
// srcs->KV dependent hop); (3) CSR slimmed to eid-only scatter.

#define FMA4(acc, s, b) do { \
    (acc).x = fmaf((s), (b).x, (acc).x); \
    (acc).y = fmaf((s), (b).y, (acc).y); \
    (acc).z = fmaf((s), (b).z, (acc).z); \
    (acc).w = fmaf((s), (b).w, (acc).w); } while (0)

// ---------------------------------------------------------------------------
// fp32 GEMM, 128x128 tile per block, 8x8 per thread, K in 4 chunks of 32.
// which=0 -> Qf[n][128]; which=1 -> K half of KV[n][256]; which=2 -> V half.
// Thread owns rows tr*8..+7, float4-cols {tc, tc+16}. Per-output-element
// arithmetic: single accumulator, fmaf, k=0..127 ascending. FROZEN.
// Hl physical layout XOR-swizzled: phys = row*8 + (k4 ^ ((row>>3)&7)).
// ---------------------------------------------------------------------------
__global__ __launch_bounds__(256) void gemm_qkv(
    const float* __restrict__ h,
    const float* __restrict__ WQ,
    const float* __restrict__ WK,
    const float* __restrict__ WV,
    float* __restrict__ Qf,
    float* __restrict__ KV,
    int N)
{
    __shared__ float4 Wl[32 * 32];   // [k][c4]            16 KB
    __shared__ float4 Hl[128 * 8];   // [row][k4] swizzled 16 KB
    const int t = threadIdx.x;
    const int which = blockIdx.y;
    const float* Wsel = (which == 0) ? WQ : ((which == 1) ? WK : WV);
    const float4* W4 = (const float4*)Wsel;
    const int r0 = blockIdx.x * 128;

    const int tc = t & 15;   // float4 cols tc and tc+16
    const int tr = t >> 4;   // rows tr*8 .. tr*8+7

    float4 acc[8][2];
#pragma unroll
    for (int i = 0; i < 8; ++i) {
        acc[i][0] = make_float4(0.f, 0.f, 0.f, 0.f);
        acc[i][1] = make_float4(0.f, 0.f, 0.f, 0.f);
    }

    for (int kc = 0; kc < 4; ++kc) {
        __syncthreads();   // protect previous chunk's reads
#pragma unroll
        for (int i = 0; i < 4; ++i) {           // Wl: 32 k-rows x 32 float4
            const int idx = t + i * 256;
            const int k = idx >> 5, c = idx & 31;
            Wl[idx] = W4[(size_t)(kc * 32 + k) * 32 + c];
        }
#pragma unroll
        for (int i = 0; i < 4; ++i) {           // Hl: 128 rows x 8 float4
            const int idx = t + i * 256;
            const int row = idx >> 3, kk = idx & 7;
            float4 v = make_float4(0.f, 0.f, 0.f, 0.f);
            if (r0 + row < N)
                v = ((const float4*)h)[(size_t)(r0 + row) * 32 + kc * 8 + kk];
            Hl[row * 8 + (kk ^ ((row >> 3) & 7))] = v;   // swizzled store
        }
        __syncthreads();

        for (int k4 = 0; k4 < 8; ++k4) {
            const float4 b0a = Wl[(k4 * 4 + 0) * 32 + tc];
            const float4 b0b = Wl[(k4 * 4 + 0) * 32 + tc + 16];
            const float4 b1a = Wl[(k4 * 4 + 1) * 32 + tc];
            const float4 b1b = Wl[(k4 * 4 + 1) * 32 + tc + 16];
            const float4 b2a = Wl[(k4 * 4 + 2) * 32 + tc];
            const float4 b2b = Wl[(k4 * 4 + 2) * 32 + tc + 16];
            const float4 b3a = Wl[(k4 * 4 + 3) * 32 + tc];
            const float4 b3b = Wl[(k4 * 4 + 3) * 32 + tc + 16];
#pragma unroll
            for (int r = 0; r < 8; ++r) {
                const int row = tr * 8 + r;
                const float4 a = Hl[row * 8 + (k4 ^ (tr & 7))];  // swizzled read
                // per-element k order: kk = 0,1,2,3 (a.x,a.y,a.z,a.w)
                FMA4(acc[r][0], a.x, b0a); FMA4(acc[r][1], a.x, b0b);
                FMA4(acc[r][0], a.y, b1a); FMA4(acc[r][1], a.y, b1b);
                FMA4(acc[r][0], a.z, b2a); FMA4(acc[r][1], a.z, b2b);
                FMA4(acc[r][0], a.w, b3a); FMA4(acc[r][1], a.w, b3b);
            }
        }
    }

    // store: Q rows stride 32 float4; KV rows stride 64, V half offset +32.
    float4* Obase = (which == 0) ? (float4*)Qf : (float4*)KV;
    const int ostride = (which == 0) ? 32 : 64;
    const int ooff = (which == 2) ? 32 : 0;
#pragma unroll
    for (int r = 0; r < 8; ++r) {
        const int row = r0 + tr * 8 + r;
        if (row < N) {
            Obase[(size_t)row * ostride + ooff + tc]      = acc[r][0];
            Obase[(size_t)row * ostride + ooff + tc + 16] = acc[r][1];
        }
    }
}

// -------------------------- CSR build (stable by dst) ----------------------
__global__ __launch_bounds__(256) void count_deg(
    const int* __restrict__ dst, int* __restrict__ deg, int E)
{
    const int e = blockIdx.x * 256 + threadIdx.x;
    if (e < E) atomicAdd(&deg[dst[e]], 1);
}

__global__ __launch_bounds__(256) void chunk_reduce(
    const int* __restrict__ deg, int* __restrict__ csum, int N)
{
    const int t = threadIdx.x;
    const int i = blockIdx.x * 256 + t;
    int x = (i < N) ? deg[i] : 0;
#pragma unroll
    for (int off = 32; off; off >>= 1) x += __shfl_down(x, off, 64);
    __shared__ int ws[4];
    if ((t & 63) == 0) ws[t >> 6] = x;
    __syncthreads();
    if (t == 0) csum[blockIdx.x] = ws[0] + ws[1] + ws[2] + ws[3];
}

__global__ __launch_bounds__(256) void scan_chunks(
    const int* __restrict__ csum, int* __restrict__ coff, int nChunks)
{
    __shared__ int s[256];
    __shared__ int carry;
    const int t = threadIdx.x;
    if (t == 0) carry = 0;
    __syncthreads();
    for (int base = 0; base < nChunks; base += 256) {
        const int i = base + t;
        int x = (i < nChunks) ? csum[i] : 0;
        s[t] = x;
        __syncthreads();
        for (int off = 1; off < 256; off <<= 1) {
            int v = (t >= off) ? s[t - off] : 0;
            __syncthreads();
            s[t] += v;
            __syncthreads();
        }
        if (i < nChunks) coff[i] = carry + s[t] - x;  // exclusive
        __syncthreads();
        if (t == 0) carry += s[255];
        __syncthreads();
    }
}

__global__ __launch_bounds__(256) void chunk_scan(
    const int* __restrict__ deg, const int* __restrict__ coff,
    int* __restrict__ rowptr, int N)
{
    __shared__ int s[256];
    const int t = threadIdx.x;
    const int i = blockIdx.x * 256 + t;
    int x = (i < N) ? deg[i] : 0;
    s[t] = x;
    __syncthreads();
    for (int off = 1; off < 256; off <<= 1) {
        int v = (t >= off) ? s[t - off] : 0;
        __syncthreads();
        s[t] += v;
        __syncthreads();
    }
    if (i < N) rowptr[i + 1] = coff[blockIdx.x] + s[t];
    if (i == 0) rowptr[0] = 0;
}

// Scatter eids via atomic ticket (arrival order; rank fixes it).
__global__ __launch_bounds__(256) void scatter_eids(
    const int* __restrict__ dst, const int* __restrict__ rowptr,
    int* __restrict__ cur, int* __restrict__ eids, int E)
{
    const int e = blockIdx.x * 256 + threadIdx.x;
    if (e >= E) return;
    const int d = dst[e];
    const int pos = rowptr[d] + atomicAdd(&cur[d], 1);
    eids[pos] = e;
}

// Wave-parallel stable ordering: rank(e) = #{e' in same dst : eid' < eid}.
// One wave per dst. srcs[lo+rank] = src[eid] -> ascending-eid order ==
// np.add.at order. deg > 64 serial fallback (P ~ 0 for Poisson(16)).
__global__ __launch_bounds__(256) void rank_emit(
    const int* __restrict__ rowptr, const int* __restrict__ eids,
    const int* __restrict__ src, int* __restrict__ srcs, int N)
{
    const int wave = threadIdx.x >> 6;
    const int lane = threadIdx.x & 63;
    const int d = blockIdx.x * 4 + wave;
    if (d >= N) return;
    const int lo = rowptr[d];
    const int deg = rowptr[d + 1] - lo;
    if (deg <= 64) {
        int p = 0x7fffffff;
        if (lane < deg) p = eids[lo + lane];
        int rank = 0;
        for (int j = 0; j < deg; ++j) {
            const int kj = __shfl(p, j, 64);
            rank += (kj < p) ? 1 : 0;
        }
        if (lane < deg) srcs[lo + rank] = src[p];
    } else if (lane == 0) {
        for (int i = 0; i < deg; ++i) {
            const int pi = eids[lo + i];
            int rank = 0;
            for (int j = 0; j < deg; ++j) rank += (eids[lo + j] < pi) ? 1 : 0;
            srcs[lo + rank] = src[pi];
        }
    }
}

// ------------------- np.add.at-order fp32 edge accumulation ----------------
// FROZEN per channel: sc = (k*q)*0.25f; z += sc; wv += v*sc, edges ascending.
// One wave per dst (2 waves/block); thread owns channels {2c,2c+1}; unroll-8
// with next-batch srcs prefetched during compute (hides srcs->KV dep hop).
__global__ __launch_bounds__(128) void attn_out(
    const int* __restrict__ srcs, const int* __restrict__ rowptr,
    const float* __restrict__ KV, const float* __restrict__ Qf,
    float* __restrict__ out, int N)
{
#pragma clang fp contract(off)
    const int wave = threadIdx.x >> 6;
    const int lane = threadIdx.x & 63;
    const int d = blockIdx.x * 2 + wave;
    if (d >= N) return;
    const float2 q = ((const float2*)Qf)[(size_t)d * 64 + lane];
    const int lo = rowptr[d], hi = rowptr[d + 1];
    const float2* KV2 = (const float2*)KV;
    float2 z = make_float2(0.f, 0.f), wv = z;

#define EDGE_UPD(k, v) do { \
        float sc0 = ((k).x * q.x) * 0.25f; z.x = z.x + sc0; wv.x = wv.x + (v).x * sc0; \
        float sc1 = ((k).y * q.y) * 0.25f; z.y = z.y + sc1; wv.y = wv.y + (v).y * sc1; \
    } while (0)

    int i = lo;
    int s[8];
    bool have = (i + 8 <= hi);
    if (have) {
#pragma unroll
        for (int u = 0; u < 8; ++u) s[u] = srcs[i + u];
    }
    while (have) {
        float2 kk[8], vv[8];
#pragma unroll
        for (int u = 0; u < 8; ++u) {
            kk[u] = KV2[(size_t)s[u] * 128 + lane];
            vv[u] = KV2[(size_t)s[u] * 128 + 64 + lane];
        }
        const int i2 = i + 8;
        const bool have2 = (i2 + 8 <= hi);
        int s2[8];
        if (have2) {
#pragma unroll
            for (int u = 0; u < 8; ++u) s2[u] = srcs[i2 + u];
        }
#pragma unroll
        for (int u = 0; u < 8; ++u) EDGE_UPD(kk[u], vv[u]);
        i = i2;
        have = have2;
        if (have2) {
#pragma unroll
            for (int u = 0; u < 8; ++u) s[u] = s2[u];
        }
    }
    for (; i + 4 <= hi; i += 4) {
        const int s0 = srcs[i + 0], s1 = srcs[i + 1];
        const int s2b = srcs[i + 2], s3 = srcs[i + 3];
        const float2 k0 = KV2[(size_t)s0 * 128 + lane], v0 = KV2[(size_t)s0 * 128 + 64 + lane];
        const float2 k1 = KV2[(size_t)s1 * 128 + lane], v1 = KV2[(size_t)s1 * 128 + 64 + lane];
        const float2 k2 = KV2[(size_t)s2b * 128 + lane], v2 = KV2[(size_t)s2b * 128 + 64 + lane];
        const float2 k3 = KV2[(size_t)s3 * 128 + lane], v3 = KV2[(size_t)s3 * 128 + 64 + lane];
        EDGE_UPD(k0, v0); EDGE_UPD(k1, v1); EDGE_UPD(k2, v2); EDGE_UPD(k3, v3);
    }
    for (; i < hi; ++i) {
        const int sx = srcs[i];
        const float2 k = KV2[(size_t)sx * 128 + lane], v = KV2[(size_t)sx * 128 + 64 + lane];
        EDGE_UPD(k, v);
    }
#undef EDGE_UPD

    float2 o;
    o.x = wv.x / (z.x + 1e-6f);
    o.y = wv.y / (z.y + 1e-6f);
    ((float2*)out)[(size_t)d * 64 + lane] = o;
}

extern "C" void kernel_launch(void* const* d_in, const int* in_sizes, int n_in,
                              void* d_out, int out_size, void* d_ws, size_t ws_size,
                              hipStream_t stream)
{
    const float* h  = (const float*)d_in[0];
    const int* src  = (const int*)d_in[1];
    const int* dst  = (const int*)d_in[2];
    const float* WQ = (const float*)d_in[3];
    const float* WK = (const float*)d_in[4];
    const float* WV = (const float*)d_in[5];
    const int N = in_sizes[0] / 128;   // 40000
    const int E = in_sizes[1];         // 640000
    const size_t NC = (size_t)N * 128;
    const int nChunks = (N + 255) / 256;

    // Workspace (~75 MB).
    float* KV = (float*)d_ws;          // N*256 f32
    float* Qf = KV + (size_t)N * 256;  // N*128 f32
    int* deg    = (int*)(Qf + NC);     // N
    int* cur    = deg + N;             // N
    int* rowptr = cur + N;             // N+1
    int* csum   = rowptr + (N + 1);    // nChunks
    int* coff   = csum + nChunks;      // nChunks
    int* srcs   = coff + nChunks;      // E
    int* eids   = srcs + E;            // E
    float* outp = (float*)d_out;

    hipMemsetAsync(deg, 0, (size_t)2 * N * sizeof(int), stream);  // deg + cur

    dim3 ggrid((N + 127) / 128, 3);
    gemm_qkv<<<ggrid, 256, 0, stream>>>(h, WQ, WK, WV, Qf, KV, N);

    const int eb = (E + 255) / 256;
    count_deg<<<eb, 256, 0, stream>>>(dst, deg, E);
    chunk_reduce<<<nChunks, 256, 0, stream>>>(deg, csum, N);
    scan_chunks<<<1, 256, 0, stream>>>(csum, coff, nChunks);
    chunk_scan<<<nChunks, 256, 0, stream>>>(deg, coff, rowptr, N);
    scatter_eids<<<eb, 256, 0, stream>>>(dst, rowptr, cur, eids, E);
    rank_emit<<<(N + 3) / 4, 256, 0, stream>>>(rowptr, eids, src, srcs, N);

    attn_out<<<(N + 1) / 2, 128, 0, stream>>>(srcs, rowptr, KV, Qf, outp, N);
}